// Round 14
// baseline (1566.800 us; speedup 1.0000x reference)
//
#include <hip/hip_runtime.h>

#define VV 50257
#define DD 50
#define TT 1024
#define BB 1024

typedef float v2f __attribute__((ext_vector_type(2)));
typedef float v4f __attribute__((ext_vector_type(4)));

__device__ __forceinline__ float rl(float v, int lane) {
    return __int_as_float(__builtin_amdgcn_readlane(__float_as_int(v), lane));
}
__device__ __forceinline__ float sigmf(float x) { return 1.0f / (1.0f + __expf(-x)); }
__device__ __forceinline__ float tanhf_fast(float x) {
    float e = __expf(-2.0f * fabsf(x));
    return copysignf((1.0f - e) / (1.0f + e), x);
}
__device__ __forceinline__ v2f mk2(float a, float b) { v2f r; r.x = a; r.y = b; return r; }
// packed fp32: 2 MACs/instruction (VOP3P). acc.[lo,hi] += s.[lo,hi]*w.[lo,hi]
__device__ __forceinline__ void pkfma(v2f& a, v2f s, v2f w) {
    asm("v_pk_fma_f32 %0, %1, %2, %0" : "+v"(a) : "v"(s), "v"(w));
}

// P1[v][j] = b1[0][j] + sum_d emb[v][d] * kx1[d][j]   (one-time, ~0.5 GFLOP)
__global__ void proj_emb(const float* __restrict__ emb, const float* __restrict__ kx1,
                         const float* __restrict__ b1, float* __restrict__ P1) {
    int j = threadIdx.x;             // 0..95
    int v0 = blockIdx.x * 8;
    #pragma unroll 1
    for (int vv = 0; vv < 8; ++vv) {
        int v = v0 + vv;
        if (v >= VV) return;
        float acc = b1[j];
        #pragma unroll
        for (int d = 0; d < DD; ++d)
            acc += emb[v * DD + d] * kx1[d * 96 + j];
        P1[v * 96 + j] = acc;
    }
}

// r13 structure (best: 1025 us, absmax 0.0) with ONE isolated change: all hot-loop
// matvecs use v_pk_fma_f32 (2 MACs/instr; numerics verified in r10). Broadcast
// v4f reads split into .xy/.zw pairs; weights pre-paired over adjacent k.
//  Wave A (wv=0): pre: m(t)=h2(t-1)·kh2+b2[1] via 96 pk_fma (was 192 fma),
//    h2(t-1) broadcast from h2s. post: x(t) from ring, gates -> h2(t), write h2s.
//  Wave B (wv=1): pre at iter t: ONE h1(t) broadcast feeds x(t)=h1(t)·kx2+b2[0]
//    (48 pk_fma -> ring slot t&3) AND GRU1 h1(t)->h1(t+1) (32 pk_fma), publish
//    h1s; prefetch p(t+2).
//  Ring safety: slot t&3 written pre-barrier of t, read post-barrier of t,
//  rewritten pre of t+4. Warmup/tail guards identical to r13.
__global__ __launch_bounds__(128, 1)
void rnn_main(const int* __restrict__ tokens, const float* __restrict__ P1,
              const float* __restrict__ kh1, const float* __restrict__ b1,
              const float* __restrict__ kx2, const float* __restrict__ kh2,
              const float* __restrict__ b2, const float* __restrict__ wg,
              const float* __restrict__ bg, const float* __restrict__ wd,
              const float* __restrict__ bd, float* __restrict__ out) {
    const int lane = threadIdx.x & 63;
    const int wv   = threadIdx.x >> 6;        // 0 = GRU2 wave, 1 = GRU1+proj wave
    const int row  = blockIdx.x;
    const int l32  = lane & 31;
    const int* __restrict__ trow = tokens + row * TT;

    __shared__ float4 xb[4][64];              // ring of x-triples
    __shared__ __align__(16) float h2s[64];   // h2 broadcast buffer (wave A only)
    __shared__ __align__(16) float h1s[32];   // h1 broadcast buffer (wave B only)

    // weight pairs: wave A uses wp[96] (z/r/h triples over k-pairs);
    // wave B uses wp[0..47] = kx2 triples over k-pairs, w1z[16], w1h[16] = kh1.
    v2f wp[96];
    v2f w1z[16], w1h[16];
    float f0, f1, f2, f3 = 0.f, f4 = 0.f;     // role-dependent biases

    if (wv == 0) {
        h2s[lane] = 0.f;                      // h2(-1) = 0
        #pragma unroll
        for (int p = 0; p < 32; ++p) {
            const int k0 = 2 * p, k1 = 2 * p + 1;
            wp[3 * p]     = mk2(kh2[k0 * 192 + lane],       kh2[k1 * 192 + lane]);
            wp[3 * p + 1] = mk2(kh2[k0 * 192 + 64 + lane],  kh2[k1 * 192 + 64 + lane]);
            wp[3 * p + 2] = mk2(kh2[k0 * 192 + 128 + lane], kh2[k1 * 192 + 128 + lane]);
        }
        f0 = b2[192 + lane];                  // recurrent biases b2[1]
        f1 = b2[256 + lane];
        f2 = b2[320 + lane];
    } else {
        if (lane < 32) h1s[lane] = 0.f;       // h1(-1) = 0
        #pragma unroll
        for (int p = 0; p < 16; ++p) {
            const int k0 = 2 * p, k1 = 2 * p + 1;
            w1z[p] = mk2(kh1[k0 * 96 + lane], kh1[k1 * 96 + lane]);
            w1h[p] = (lane < 32) ? mk2(kh1[k0 * 96 + 64 + lane], kh1[k1 * 96 + 64 + lane])
                                 : mk2(0.f, 0.f);
            wp[3 * p]     = mk2(kx2[k0 * 192 + lane],       kx2[k1 * 192 + lane]);
            wp[3 * p + 1] = mk2(kx2[k0 * 192 + 64 + lane],  kx2[k1 * 192 + 64 + lane]);
            wp[3 * p + 2] = mk2(kx2[k0 * 192 + 128 + lane], kx2[k1 * 192 + 128 + lane]);
        }
        f0 = b1[96 + lane];                   // GRU1 recurrent z/r bias
        f1 = (lane < 32) ? b1[160 + lane] : 0.f;   // GRU1 recurrent h bias
        f2 = b2[lane];                        // input-proj biases b2[0]
        f3 = b2[64 + lane];
        f4 = b2[128 + lane];
    }

    float h1 = 0.f, h2 = 0.f;                 // per-lane state registers
    float pz = 0.f, pr = 0.f, ph = 0.f;
    int tokc = 0;
    if (wv == 1) {                            // p-triple for GRU1 step 0
        const float* __restrict__ p = P1 + trow[0] * 96;
        pz = p[l32]; pr = p[32 + l32]; ph = p[64 + l32];
        tokc = trow[1];                       // token for p(t+2) prefetch at t=-1
    }

    v2f mzp, mrp, mhp;                        // wave A accumulators (pre -> post)

    #pragma unroll 1
    for (int t = -1; t < TT; ++t) {
        // ---------------- pre-barrier ----------------
        if (wv == 0) {
            if (t >= 0) {
                // m(t) = h2(t-1)·kh2 + b2[1], h2(t-1) broadcast from LDS
                const v4f* __restrict__ h2v = reinterpret_cast<const v4f*>(h2s);
                mzp = mk2(0.f, 0.f); mrp = mzp; mhp = mzp;
                #pragma unroll
                for (int kc = 0; kc < 16; ++kc) {
                    v4f hb = h2v[kc];
                    v2f lo = hb.xy, hi = hb.zw;
                    const int pA = 3 * (2 * kc), pB = 3 * (2 * kc + 1);
                    pkfma(mzp, lo, wp[pA]);     pkfma(mrp, lo, wp[pA + 1]); pkfma(mhp, lo, wp[pA + 2]);
                    pkfma(mzp, hi, wp[pB]);     pkfma(mrp, hi, wp[pB + 1]); pkfma(mhp, hi, wp[pB + 2]);
                }
            }
        } else if (t < TT) {
            // broadcast h1(t) (written by this wave at iter t-1; init for t=-1)
            const v4f* __restrict__ h1v = reinterpret_cast<const v4f*>(h1s);
            v4f hb[8];
            #pragma unroll
            for (int kc = 0; kc < 8; ++kc) hb[kc] = h1v[kc];
            if (t >= 0) {
                // x(t) = h1(t)·kx2 + b2[0]  -> ring slot t&3
                v2f xzp = mk2(0.f, 0.f), xrp = xzp, xhp = xzp;
                #pragma unroll
                for (int kc = 0; kc < 8; ++kc) {
                    v2f lo = hb[kc].xy, hi = hb[kc].zw;
                    const int pA = 3 * (2 * kc), pB = 3 * (2 * kc + 1);
                    pkfma(xzp, lo, wp[pA]);     pkfma(xrp, lo, wp[pA + 1]); pkfma(xhp, lo, wp[pA + 2]);
                    pkfma(xzp, hi, wp[pB]);     pkfma(xrp, hi, wp[pB + 1]); pkfma(xhp, hi, wp[pB + 2]);
                }
                xb[t & 3][lane] = make_float4(xzp.x + xzp.y + f2, xrp.x + xrp.y + f3,
                                              xhp.x + xhp.y + f4, 0.f);
            }
            if (t < TT - 1) {
                // GRU1: h1(t) -> h1(t+1) using p(t+1)
                v2f azp = mk2(0.f, 0.f), ahp = azp;
                #pragma unroll
                for (int kc = 0; kc < 8; ++kc) {
                    v2f lo = hb[kc].xy, hi = hb[kc].zw;
                    pkfma(azp, lo, w1z[2 * kc]);     pkfma(ahp, lo, w1h[2 * kc]);
                    pkfma(azp, hi, w1z[2 * kc + 1]); pkfma(ahp, hi, w1h[2 * kc + 1]);
                }
                float az = azp.x + azp.y + f0;
                float ah = ahp.x + ahp.y + f1;
                float ra  = __shfl_xor(az, 32);   // r-preact to lanes 0..31
                float z1  = sigmf(pz + az);
                float g1  = sigmf(pr + ra);
                float hh1 = tanhf_fast(ph + g1 * ah);
                h1 = z1 * h1 + (1.f - z1) * hh1;  // h1(t+1) per-lane
                if (lane < 32) h1s[lane] = h1;    // publish broadcast copy
                // prefetch p(t+2), token(t+3)
                const float* __restrict__ pn = P1 + tokc * 96;
                pz = pn[l32]; pr = pn[32 + l32]; ph = pn[64 + l32];
                tokc = trow[(t + 3 < TT) ? (t + 3) : (TT - 1)];
            }
        }
        __syncthreads();
        // ---------------- post-barrier ----------------
        if (wv == 0 && t >= 0) {
            float4 x  = xb[t & 3][lane];
            float mz  = mzp.x + mzp.y + f0;
            float mr  = mrp.x + mrp.y + f1;
            float mh  = mhp.x + mhp.y + f2;
            float z2  = sigmf(x.x + mz);
            float r2  = sigmf(x.y + mr);
            float hh2 = tanhf_fast(x.z + r2 * mh);   // reset after recurrent mm
            h2 = z2 * h2 + (1.f - z2) * hh2;
            h2s[lane] = h2;                          // publish for next pre-phase
        }
    }

    // ---- tail: GLU + dense head, wave A only (holds h2) ----
    if (wv == 0) {
        float a0 = bg[lane], a1 = bg[64 + lane], a2 = bg[128 + lane], a3 = bg[192 + lane];
        #pragma unroll
        for (int k = 0; k < 64; ++k) {
            float s = rl(h2, k);
            a0 += s * wg[k * 256 + lane];
            a1 += s * wg[k * 256 + 64 + lane];
            a2 += s * wg[k * 256 + 128 + lane];
            a3 += s * wg[k * 256 + 192 + lane];
        }
        float g = a0 * sigmf(a2) * wd[lane] + a1 * sigmf(a3) * wd[64 + lane];
        g += __shfl_xor(g, 32); g += __shfl_xor(g, 16); g += __shfl_xor(g, 8);
        g += __shfl_xor(g, 4);  g += __shfl_xor(g, 2);  g += __shfl_xor(g, 1);
        if (lane == 0) out[row] = sigmf(g + bd[0]);
    }
}

extern "C" void kernel_launch(void* const* d_in, const int* in_sizes, int n_in,
                              void* d_out, int out_size, void* d_ws, size_t ws_size,
                              hipStream_t stream) {
    const int*   tokens = (const int*)d_in[0];
    const float* emb = (const float*)d_in[1];
    const float* kx1 = (const float*)d_in[2];
    const float* kh1 = (const float*)d_in[3];
    const float* b1  = (const float*)d_in[4];
    const float* kx2 = (const float*)d_in[5];
    const float* kh2 = (const float*)d_in[6];
    const float* b2  = (const float*)d_in[7];
    const float* wg  = (const float*)d_in[8];
    const float* bg  = (const float*)d_in[9];
    const float* wd  = (const float*)d_in[10];
    const float* bd  = (const float*)d_in[11];
    float* out = (float*)d_out;
    float* P1  = (float*)d_ws;   // needs 50257*96*4 = 19.3 MB of workspace

    proj_emb<<<(VV + 7) / 8, 96, 0, stream>>>(emb, kx1, b1, P1);
    rnn_main<<<BB, 128, 0, stream>>>(tokens, P1, kh1, b1, kx2, kh2, b2,
                                     wg, bg, wd, bd, out);
}